// Round 4
// baseline (818.567 us; speedup 1.0000x reference)
//
#include <hip/hip_runtime.h>
#include <stdint.h>

// Softmax-Viterbi forward, 1024x1024, S=4.
// R12: software-pipeline the CHAIN. Evidence: R9/R10/R11 all changed the feed
// structure (heaters, 8 on-CU producers, off-CU producers+loaders) and all
// landed at ~683-695us profiled -> feed never was the bottleneck. Chain runs
// ~740 cy/step vs ~200 modeled; VALUBusy ~1.1% (chain issues ~15% of cycles)
// and VGPR_Count=88 (too low for hoisted loads) say the compiler issues the
// per-step ds_reads just-in-time -> ~120cy LDS latency + acquire-drains
// exposed EVERY step. Fix: explicit double-buffered register staging of a
// full half-chunk (pA/pB: 4 steps x {4xfloat4 P + float4+int rec}); spins for
// half h+1 run before its loads; loads overlap compute of half h from regs.
// Statically-named buffers, h+=2 loop for compile-time parity.
// Producers / loaders / comms / ws layout: unchanged from R11.

#define MM    1024
#define LOG2E 1.4426950408889634f
#define LN2f  0.6931471805599453f
#define NEGI  (-1073741824)
#define CH    8
#define NCH   136
#define HCT   (NCH*2)                // 272 half-chunks, 4 steps each
#define DEPTH 32                     // global P-ring depth in half-chunks
#define PPS   15                     // producer blocks per strip

#define F_RIN   0
#define F_CDONE 1
#define F_OPUB  2
#define F_PD    4                    // F_PD + (h&7): LDS slot ready flags

__device__ __forceinline__ float ld_cohf(const float* p) {
    return __hip_atomic_load(p, __ATOMIC_RELAXED, __HIP_MEMORY_SCOPE_AGENT);
}
__device__ __forceinline__ int ld_cohi(const int* p) {
    return __hip_atomic_load(p, __ATOMIC_RELAXED, __HIP_MEMORY_SCOPE_AGENT);
}
__device__ __forceinline__ void st_cohf(float* p, float v) {
    __hip_atomic_store(p, v, __ATOMIC_RELAXED, __HIP_MEMORY_SCOPE_AGENT);
}
__device__ __forceinline__ void st_cohi(int* p, int v) {
    __hip_atomic_store(p, v, __ATOMIC_RELAXED, __HIP_MEMORY_SCOPE_AGENT);
}
__device__ __forceinline__ int lds_acq(const int* p) {
    return __hip_atomic_load(p, __ATOMIC_ACQUIRE, __HIP_MEMORY_SCOPE_WORKGROUP);
}
__device__ __forceinline__ void lds_rel(int* p, int v) {
    __hip_atomic_store(p, v, __ATOMIC_RELEASE, __HIP_MEMORY_SCOPE_WORKGROUP);
}

// DPP wave_shr1: lane n <- lane n-1; lane 0 <- oldv (bound_ctrl=false keeps old).
__device__ __forceinline__ int dpp_shr1_i(int oldv, int src) {
    return __builtin_amdgcn_update_dpp(oldv, src, 0x138, 0xF, 0xF, false);
}
__device__ __forceinline__ float dpp_shr1_f(float oldv, float src) {
    return __int_as_float(__builtin_amdgcn_update_dpp(
        __float_as_int(oldv), __float_as_int(src), 0x138, 0xF, 0xF, false));
}

// ---- chain macros: spin / load / compute one half-chunk (4 steps) ----------
#define SPINHALF(H) do {                                                      \
    if (((H) & 1) == 0) {                                                     \
        const int cc_ = (H) >> 1;                                             \
        if (isCons) while (lds_acq(&flags[F_RIN]) < cc_) {}                   \
        if (isProd) while (lds_acq(&flags[F_OPUB]) < cc_ - 3) {}              \
    }                                                                         \
    while (lds_acq(&flags[F_PD + ((H) & 7)]) < (H)) {}                        \
} while (0)

#define LOADHALF(H, PX, RX, MX) do {                                          \
    const int b_  = (H) & 7;                                                  \
    const int sb_ = (((H) >> 1) & 3) * 8 + ((H) & 1) * 4;                     \
    _Pragma("unroll")                                                         \
    for (int u_ = 0; u_ < 4; ++u_) {                                          \
        PX[u_][0] = ldsP[b_][u_][0][lane];                                    \
        PX[u_][1] = ldsP[b_][u_][1][lane];                                    \
        PX[u_][2] = ldsP[b_][u_][2][lane];                                    \
        PX[u_][3] = ldsP[b_][u_][3][lane];                                    \
        if (isCons) {                                                         \
            RX[u_] = *(const float4*)&recIn[sb_ + u_][0];                     \
            MX[u_] = __float_as_int(recIn[sb_ + u_][4]);                      \
        } else {                                                              \
            RX[u_] = make_float4(0.f, 0.f, 0.f, 0.f);                         \
            MX[u_] = NEGI;                                                    \
        }                                                                     \
    }                                                                         \
} while (0)

#define COMPUTEHALF(H, PX, RX, MX) do {                                       \
    const int sb_ = (((H) >> 1) & 3) * 8 + ((H) & 1) * 4;                     \
    _Pragma("unroll")                                                         \
    for (int u_ = 0; u_ < 4; ++u_) {                                          \
        const int tau_ = (H) * 4 + u_;                                        \
        const int jq_  = tau_ - r + 1;                                        \
        float4 P0 = PX[u_][0], P1 = PX[u_][1];                                \
        float4 P2 = PX[u_][2], P3 = PX[u_][3];                                \
        int off = max(max(mD, mU), mL);                                       \
        float sd = ldexpf(1.0f, mD - off);                                    \
        float su = ldexpf(1.0f, mU - off);                                    \
        float sl = ldexpf(1.0f, mL - off);                                    \
        float dm  = fmaf(qd1,P0.y, qd0*P0.x) + fmaf(qd3,P0.w, qd2*P0.z);      \
        float dx  = fmaf(qu1,P1.y, qu0*P1.x) + fmaf(qu3,P1.w, qu2*P1.z);      \
        float dy  = fmaf(ql1,P2.y, ql0*P2.x) + fmaf(ql3,P2.w, ql2*P2.z);      \
        float ds2 = fmaf(qd1,P3.y, qd0*P3.x) + fmaf(qd3,P3.w, qd2*P3.z);      \
        float g0 = dm *sd;                                                    \
        float g1 = dx *su;                                                    \
        float g2 = dy *sl;                                                    \
        float g3 = ds2*sd;                                                    \
        float gmax = fmaxf(fmaxf(g0,g1), fmaxf(g2,g3));                       \
        int e = (int)(__float_as_uint(gmax) >> 23) - 126;                     \
        float qn0 = ldexpf(g0, 1-e), qn1 = ldexpf(g1, 1-e);                   \
        float qn2 = ldexpf(g2, 1-e), qn3 = ldexpf(g3, 1-e);                   \
        int mn = off + e - 1;                                                 \
        const bool valid_ = (jq_ >= 1) && (jq_ <= MM);                        \
        if (!valid_) { qn0=qn1=qn2=qn3=0.f; mn=NEGI; }                        \
        if (lane == 63) {                                                     \
            if (isProd) {                                                     \
                *(float4*)&recOut[sb_ + u_][0] = make_float4(qn0,qn1,qn2,qn3);\
                recOut[sb_ + u_][4] = __int_as_float(mn);                     \
            } else if (jq_ == MM) {                                           \
                out[0] = LN2f * ((float)mn + log2f((qn0+qn1)+(qn2+qn3)));     \
            }                                                                 \
        }                                                                     \
        mD = mU; qd0=qu0; qd1=qu1; qd2=qu2; qd3=qu3;                          \
        mU  = dpp_shr1_i(MX[u_], mn);                                         \
        qu0 = dpp_shr1_f(RX[u_].x, qn0);                                      \
        qu1 = dpp_shr1_f(RX[u_].y, qn1);                                      \
        qu2 = dpp_shr1_f(RX[u_].z, qn2);                                      \
        qu3 = dpp_shr1_f(RX[u_].w, qn3);                                      \
        mL = mn; ql0=qn0; ql1=qn1; ql2=qn2; ql3=qn3;                          \
    }                                                                         \
    if (lane == 0) lds_rel(&flags[F_CDONE], (H));                             \
} while (0)

__global__ __launch_bounds__(384, 1) void viterbi_r12(
    const float* __restrict__ theta, const float* __restrict__ A,
    float* __restrict__ out, float* __restrict__ bnd, int* __restrict__ prog,
    int* __restrict__ cpG, int* __restrict__ rfG, float* __restrict__ ringG)
{
    // Static LDS in every block (incl. producers) -> guarantees 1 block/CU.
    __shared__ float4 ldsP[8][4][4][64];    // 128 KB: [hc&7][tau][plane][row]
    __shared__ float  recIn[32][8];
    __shared__ float  recOut[32][8];
    __shared__ int    flags[16];

    const int tid  = threadIdx.x;
    const int wv   = tid >> 6;
    const int lane = tid & 63;
    const int bid  = blockIdx.x;

    if (tid < 16) flags[tid] = -1;
    __syncthreads();

    if (bid >= 16) {
        // ===================== producer blocks =====================
        if (wv >= 4) return;                 // waves 4,5 unused here
        const int k     = bid & 7;           // XCD (heuristic)
        const int idx   = (bid - 16) >> 3;   // 0..29 within XCD
        const int s     = 2*k + (idx >= PPS);
        const int pslot = idx % PPS;
        const int u2    = wv;                // tau within hc
        const int row   = s*64 + lane;
        const float4* A4 = (const float4*)A;
        const float4* T4 = (const float4*)theta;
        const int* cp = cpG + s*16;
        for (int h = pslot; h < HCT; h += PPS) {
            while (ld_cohi(cp) < h - DEPTH) __builtin_amdgcn_s_sleep(1);
            const int tau = 4*h + u2;
            int c = tau - lane; c = c < 0 ? 0 : (c > MM-1 ? MM-1 : c);
            const float4* Ar = A4 + ((size_t)row*MM + (size_t)c)*4;
            float4 a0 = Ar[0], a1 = Ar[1], a2 = Ar[2], a3 = Ar[3];
            float4 th = T4[(size_t)row*MM + (size_t)c];
            float4 p0, p1, p2, p3;       // theta-folded exp-domain potentials
            p0.x=exp2f((a0.x+th.x)*LOG2E); p0.y=exp2f((a0.y+th.x)*LOG2E);
            p0.z=exp2f((a0.z+th.x)*LOG2E); p0.w=exp2f((a0.w+th.x)*LOG2E);
            p1.x=exp2f((a1.x+th.y)*LOG2E); p1.y=exp2f((a1.y+th.y)*LOG2E);
            p1.z=exp2f((a1.z+th.y)*LOG2E); p1.w=exp2f((a1.w+th.y)*LOG2E);
            p2.x=exp2f((a2.x+th.z)*LOG2E); p2.y=exp2f((a2.y+th.z)*LOG2E);
            p2.z=exp2f((a2.z+th.z)*LOG2E); p2.w=exp2f((a2.w+th.z)*LOG2E);
            p3.x=exp2f((a3.x+th.w)*LOG2E); p3.y=exp2f((a3.y+th.w)*LOG2E);
            p3.z=exp2f((a3.z+th.w)*LOG2E); p3.w=exp2f((a3.w+th.w)*LOG2E);
            // slot layout matches LDS: float4 index (u2*4+plane)*64 + lane
            float* dst = ringG + ((size_t)(s*DEPTH + (h & (DEPTH-1))) << 12)
                               + (size_t)((u2*4)*64 + lane)*4;
            st_cohf(dst+0,   p0.x); st_cohf(dst+1,   p0.y);
            st_cohf(dst+2,   p0.z); st_cohf(dst+3,   p0.w);
            st_cohf(dst+256, p1.x); st_cohf(dst+257, p1.y);
            st_cohf(dst+258, p1.z); st_cohf(dst+259, p1.w);
            st_cohf(dst+512, p2.x); st_cohf(dst+513, p2.y);
            st_cohf(dst+514, p2.z); st_cohf(dst+515, p2.w);
            st_cohf(dst+768, p3.x); st_cohf(dst+769, p3.y);
            st_cohf(dst+770, p3.z); st_cohf(dst+771, p3.w);
            asm volatile("s_waitcnt vmcnt(0)" ::: "memory");
            if (lane == 0)
                st_cohi(rfG + (size_t)(s*DEPTH + (h & (DEPTH-1)))*16 + u2, h);
        }
        return;
    }

    // ===================== pipeline blocks =====================
    const int strip = ((bid & 7) << 1) | (bid >> 3);   // strip s on XCD s>>1
    const bool isCons = (strip > 0);
    const bool isProd = (strip < 15);

    float* Prec = bnd + (size_t)strip * MM * 8;
    const float* Crec = bnd + (size_t)(strip - 1) * MM * 8;
    int* myflag = prog + strip * 32;
    const int* upflag = prog + (strip - 1) * 32;

    if (wv == 0) {
        // ============ chain wave: double-buffered register pipeline =========
        __builtin_amdgcn_s_setprio(1);
        const int r = lane;
        int   mL = NEGI, mU = NEGI, mD = NEGI;
        float ql0=0,ql1=0,ql2=0,ql3=0;
        float qu0=0,qu1=0,qu2=0,qu3=0;
        float qd0=0,qd1=0,qd2=0,qd3=0;
        if (strip == 0 && lane == 0) { mD = 0; qd0=qd1=qd2=qd3=1.f; }
        if (isCons) {
            while (ld_cohi(upflag) < 1) __builtin_amdgcn_s_sleep(1);
            asm volatile("" ::: "memory");
            qu0 = ld_cohf(Crec+0); qu1 = ld_cohf(Crec+1);
            qu2 = ld_cohf(Crec+2); qu3 = ld_cohf(Crec+3);
            mU  = ld_cohi((const int*)Crec + 4);
        }
        float4 pA[4][4], pB[4][4];
        float4 rA[4], rB[4];
        int    mA[4], mB[4];
        SPINHALF(0);
        LOADHALF(0, pA, rA, mA);
        for (int h = 0; h < HCT; h += 2) {
            SPINHALF(h + 1);
            LOADHALF(h + 1, pB, rB, mB);        // loads overlap compute of h
            COMPUTEHALF(h, pA, rA, mA);
            if (h + 2 < HCT) {
                SPINHALF(h + 2);
                LOADHALF(h + 2, pA, rA, mA);    // loads overlap compute of h+1
            }
            COMPUTEHALF(h + 1, pB, rB, mB);
        }
    } else if (wv <= 3) {
        // ===================== loader waves (ring -> LDS) ===================
        const int L = wv - 1;                 // 0..2, handles h == L (mod 3)
        int* cp = cpG + strip*16;
        for (int h = L; h < HCT; h += 3) {
            if (L == 0) st_cohi(cp, lds_acq(&flags[F_CDONE]));  // pace producers
            while (lds_acq(&flags[F_CDONE]) < h - 8) {}         // LDS slot free
            const int slot = h & (DEPTH-1);
            const int buf  = h & 7;
            const int* rf = rfG + (size_t)(strip*DEPTH + slot)*16;
            while (ld_cohi(rf+0) < h || ld_cohi(rf+1) < h ||
                   ld_cohi(rf+2) < h || ld_cohi(rf+3) < h) {}
            asm volatile("" ::: "memory");
            const float* src = ringG + ((size_t)(strip*DEPTH + slot) << 12)
                                     + (size_t)lane*4;
            float4 q[16];
#pragma unroll
            for (int i = 0; i < 16; ++i) {
                const float* sp = src + i*256;
                q[i].x = ld_cohf(sp+0); q[i].y = ld_cohf(sp+1);
                q[i].z = ld_cohf(sp+2); q[i].w = ld_cohf(sp+3);
            }
            float4* dst = &ldsP[buf][0][0][0];
#pragma unroll
            for (int i = 0; i < 16; ++i) dst[i*64 + lane] = q[i];
            lds_rel(&flags[F_PD + buf], h);
        }
        if (L == 0) st_cohi(cp, HCT);         // final pace post
    } else if (wv == 4) {
        // ===================== out-comms wave =====================
        if (!isProd) return;
        const int rec0 = lane / 5, wd0 = lane % 5;
        const int rec1 = (lane+64) / 5, wd1 = (lane+64) % 5;
        const bool on1 = (lane + 64) < 80;
        for (int cc = 0; cc < NCH; cc += 2) {
            while (lds_acq(&flags[F_CDONE]) < 2*cc + 3) __builtin_amdgcn_s_sleep(1);
            {
                int col = 8*(cc + (rec0 >> 3)) + (rec0 & 7) - 62;
                float v = recOut[(cc & 3)*8 + rec0][wd0];
                if (col >= 1 && col <= MM) st_cohf(Prec + (size_t)(col-1)*8 + wd0, v);
            }
            if (on1) {
                int col = 8*(cc + (rec1 >> 3)) + (rec1 & 7) - 62;
                float v = recOut[(cc & 3)*8 + rec1][wd1];
                if (col >= 1 && col <= MM) st_cohf(Prec + (size_t)(col-1)*8 + wd1, v);
            }
            asm volatile("s_waitcnt vmcnt(0)" ::: "memory");
            int done = 8*(cc + 1) - 55; if (done > MM) done = MM;
            if (done >= 1 && lane == 0) st_cohi(myflag, done);
            if (lane == 0) lds_rel(&flags[F_OPUB], cc + 1);
        }
    } else {
        // ===================== in-comms wave =====================
        if (!isCons) return;
        const int rec0 = lane / 5, wd0 = lane % 5;
        const int rec1 = (lane+64) / 5, wd1 = (lane+64) % 5;
        const bool on1 = (lane + 64) < 80;
        for (int cc = 0; cc < NCH; cc += 2) {
            while (lds_acq(&flags[F_CDONE]) < 2*cc - 3) __builtin_amdgcn_s_sleep(1);
            int need = 8*cc + 17; if (need > MM) need = MM;
            while (ld_cohi(upflag) < need) __builtin_amdgcn_s_sleep(1);
            asm volatile("" ::: "memory");
            {
                int col = 8*cc + 2 + rec0; if (col > MM) col = MM;
                float v = ld_cohf(Crec + (size_t)(col-1)*8 + wd0);
                recIn[(cc & 3)*8 + rec0][wd0] = v;
            }
            if (on1) {
                int col = 8*cc + 2 + rec1; if (col > MM) col = MM;
                float v = ld_cohf(Crec + (size_t)(col-1)*8 + wd1);
                recIn[(cc & 3)*8 + rec1][wd1] = v;
            }
            if (lane == 0) lds_rel(&flags[F_RIN], cc + 1);
        }
    }
}

extern "C" void kernel_launch(void* const* d_in, const int* in_sizes, int n_in,
                              void* d_out, int out_size, void* d_ws, size_t ws_size,
                              hipStream_t stream) {
    const float* theta = (const float*)d_in[0];   // [1024,1024,4] f32
    const float* A     = (const float*)d_in[1];   // [1024,1024,4,4] f32
    float* out = (float*)d_out;                   // [1] f32
    // ws layout (0xAA poison -> all flags/counters negative -> safe spins):
    //   [0, 512K)        boundary records [16][1024][8] f32
    //   [512K, 512K+4K)  record progress flags prog[16*32]
    //   [+4K, +8K)       chain progress cpG[16*16] (one 64B line per strip)
    //   [+8K, +40K)      ring flags rfG[16*32*16] (one 64B line per slot)
    //   [64K-aligned 8M) P ring ringG: 16 strips * 32 slots * 16 KB
    char* base = (char*)d_ws;
    float* bnd  = (float*)base;
    int*   prog = (int*)(base + (size_t)512*1024);
    int*   cpG  = (int*)(base + (size_t)512*1024 + 4*1024);
    int*   rfG  = (int*)(base + (size_t)512*1024 + 8*1024);
    float* ring = (float*)(base + (size_t)512*1024 + 64*1024);
    viterbi_r12<<<256, 384, 0, stream>>>(theta, A, out, bnd, prog, cpG, rfG, ring);
}

// Round 5
// 666.751 us; speedup vs baseline: 1.2277x; 1.2277x over previous
//
#include <hip/hip_runtime.h>
#include <stdint.h>

// Softmax-Viterbi forward, 1024x1024, S=4.
// R13: self-feeding chain with HW-counted prefetch. R12's C-level double
// buffer was sunk by the compiler (VGPR 100, not ~220) -> load-latency theory
// never actually tested. Now binding: chain reads the P ring DIRECTLY from
// global into registers via inline-asm global_load_dwordx4 sc0 sc1, 2 hc
// ahead, ordered by counted s_waitcnt vmcnt(35/19) (18 vmem ops per body:
// 1 flag + 16 data + 1 pace store; in-order retirement makes counts exact).
// Ring flags prefetched 2 hc ahead as dwordx4 (4 ints), coherent re-poll
// fallback. Loaders + LDS P-staging + F_PD hops REMOVED; chain paces the
// producers itself (1 relaxed store/hc). Chain alone on SIMD0.
// Producers / out-comms / in-comms / ws layout: unchanged from R11.
// Blocks: 0..15 pipeline (wv0 chain, wv1 out, wv2 in, wv3 idle);
//         16..255 producers (4 waves, u2 = wv). 256 thr; 96KB dynamic LDS
//         pad forces 1 block/CU.

typedef float f32x4 __attribute__((ext_vector_type(4)));
typedef int   i32x4 __attribute__((ext_vector_type(4)));

#define MM    1024
#define LOG2E 1.4426950408889634f
#define LN2f  0.6931471805599453f
#define NEGI  (-1073741824)
#define NCH   136
#define HCT   (NCH*2)                // 272 half-chunks, 4 steps each
#define DEPTH 32                     // global P-ring depth in half-chunks
#define PPS   15                     // producer blocks per strip

#define F_RIN   0
#define F_CDONE 1
#define F_OPUB  2

__device__ __forceinline__ float ld_cohf(const float* p) {
    return __hip_atomic_load(p, __ATOMIC_RELAXED, __HIP_MEMORY_SCOPE_AGENT);
}
__device__ __forceinline__ int ld_cohi(const int* p) {
    return __hip_atomic_load(p, __ATOMIC_RELAXED, __HIP_MEMORY_SCOPE_AGENT);
}
__device__ __forceinline__ void st_cohf(float* p, float v) {
    __hip_atomic_store(p, v, __ATOMIC_RELAXED, __HIP_MEMORY_SCOPE_AGENT);
}
__device__ __forceinline__ void st_cohi(int* p, int v) {
    __hip_atomic_store(p, v, __ATOMIC_RELAXED, __HIP_MEMORY_SCOPE_AGENT);
}
__device__ __forceinline__ int lds_acq(const int* p) {
    return __hip_atomic_load(p, __ATOMIC_ACQUIRE, __HIP_MEMORY_SCOPE_WORKGROUP);
}
__device__ __forceinline__ void lds_rel(int* p, int v) {
    __hip_atomic_store(p, v, __ATOMIC_RELEASE, __HIP_MEMORY_SCOPE_WORKGROUP);
}

// DPP wave_shr1: lane n <- lane n-1; lane 0 <- oldv (bound_ctrl=false keeps old).
__device__ __forceinline__ int dpp_shr1_i(int oldv, int src) {
    return __builtin_amdgcn_update_dpp(oldv, src, 0x138, 0xF, 0xF, false);
}
__device__ __forceinline__ float dpp_shr1_f(float oldv, float src) {
    return __int_as_float(__builtin_amdgcn_update_dpp(
        __float_as_int(oldv), __float_as_int(src), 0x138, 0xF, 0xF, false));
}

// ---------------- chain-side pipeline macros ----------------
#define WAITV(N) do {                                                         \
    asm volatile("s_waitcnt vmcnt(" #N ")" ::: "memory");                     \
    __builtin_amdgcn_sched_barrier(0);                                        \
} while (0)

#define ISSUE_FLAG(FX, H) do {                                                \
    const int hf_ = ((H) < HCT ? (H) : (HCT-1));                              \
    const int* rp_ = rfS + (size_t)(hf_ & (DEPTH-1)) * 16;                    \
    asm volatile("global_load_dwordx4 %0, %1, off sc0 sc1"                    \
                 : "=v"(FX) : "v"(rp_) : "memory");                           \
} while (0)

#define CHECK_FLAG(FX, H) do {                                                \
    const int hv_ = ((H) < HCT ? (H) : (HCT-1));                              \
    if (!(FX.x >= hv_ && FX.y >= hv_ && FX.z >= hv_ && FX.w >= hv_)) {        \
        const int* rp_ = rfS + (size_t)(hv_ & (DEPTH-1)) * 16;                \
        for (;;) {                                                            \
            asm volatile("global_load_dwordx4 %0, %1, off sc0 sc1\n\t"        \
                         "s_waitcnt vmcnt(0)"                                 \
                         : "=v"(FX) : "v"(rp_) : "memory");                   \
            if (FX.x >= hv_ && FX.y >= hv_ && FX.z >= hv_ && FX.w >= hv_)     \
                break;                                                        \
            __builtin_amdgcn_s_sleep(2);                                      \
        }                                                                     \
    }                                                                         \
    asm volatile("" ::: "memory");                                            \
} while (0)

#define ISSUE_DATA(PX, H) do {                                                \
    const int hcl_ = ((H) < HCT ? (H) : (HCT-1));                             \
    const char* b0_ = ringS + ((size_t)(hcl_ & (DEPTH-1)) << 14)              \
                            + (size_t)lane * 16;                              \
    const char* b1_ = b0_ + 4096;                                             \
    const char* b2_ = b0_ + 8192;                                             \
    const char* b3_ = b0_ + 12288;                                            \
    asm volatile("global_load_dwordx4 %0, %1, off sc0 sc1"              : "=v"(PX[0])  : "v"(b0_) : "memory"); \
    asm volatile("global_load_dwordx4 %0, %1, off offset:1024 sc0 sc1"  : "=v"(PX[1])  : "v"(b0_) : "memory"); \
    asm volatile("global_load_dwordx4 %0, %1, off offset:2048 sc0 sc1"  : "=v"(PX[2])  : "v"(b0_) : "memory"); \
    asm volatile("global_load_dwordx4 %0, %1, off offset:3072 sc0 sc1"  : "=v"(PX[3])  : "v"(b0_) : "memory"); \
    asm volatile("global_load_dwordx4 %0, %1, off sc0 sc1"              : "=v"(PX[4])  : "v"(b1_) : "memory"); \
    asm volatile("global_load_dwordx4 %0, %1, off offset:1024 sc0 sc1"  : "=v"(PX[5])  : "v"(b1_) : "memory"); \
    asm volatile("global_load_dwordx4 %0, %1, off offset:2048 sc0 sc1"  : "=v"(PX[6])  : "v"(b1_) : "memory"); \
    asm volatile("global_load_dwordx4 %0, %1, off offset:3072 sc0 sc1"  : "=v"(PX[7])  : "v"(b1_) : "memory"); \
    asm volatile("global_load_dwordx4 %0, %1, off sc0 sc1"              : "=v"(PX[8])  : "v"(b2_) : "memory"); \
    asm volatile("global_load_dwordx4 %0, %1, off offset:1024 sc0 sc1"  : "=v"(PX[9])  : "v"(b2_) : "memory"); \
    asm volatile("global_load_dwordx4 %0, %1, off offset:2048 sc0 sc1"  : "=v"(PX[10]) : "v"(b2_) : "memory"); \
    asm volatile("global_load_dwordx4 %0, %1, off offset:3072 sc0 sc1"  : "=v"(PX[11]) : "v"(b2_) : "memory"); \
    asm volatile("global_load_dwordx4 %0, %1, off sc0 sc1"              : "=v"(PX[12]) : "v"(b3_) : "memory"); \
    asm volatile("global_load_dwordx4 %0, %1, off offset:1024 sc0 sc1"  : "=v"(PX[13]) : "v"(b3_) : "memory"); \
    asm volatile("global_load_dwordx4 %0, %1, off offset:2048 sc0 sc1"  : "=v"(PX[14]) : "v"(b3_) : "memory"); \
    asm volatile("global_load_dwordx4 %0, %1, off offset:3072 sc0 sc1"  : "=v"(PX[15]) : "v"(b3_) : "memory"); \
} while (0)

#define CHUNKSPIN(H) do {                                                     \
    if (((H) & 1) == 0) {                                                     \
        const int cc_ = (H) >> 1;                                             \
        if (isCons) while (lds_acq(&flags[F_RIN]) < cc_) {}                   \
        if (isProd) while (lds_acq(&flags[F_OPUB]) < cc_ - 3) {}              \
    }                                                                         \
} while (0)

#define COMPUTEHC(H, PX) do {                                                 \
    const int sb_ = (((H) >> 1) & 3) * 8 + ((H) & 1) * 4;                     \
    _Pragma("unroll")                                                         \
    for (int u_ = 0; u_ < 4; ++u_) {                                          \
        const int tau_ = (H)*4 + u_;                                          \
        const int jq_  = tau_ - r + 1;                                        \
        f32x4 P0 = PX[u_*4+0], P1 = PX[u_*4+1];                               \
        f32x4 P2 = PX[u_*4+2], P3 = PX[u_*4+3];                               \
        int off = max(max(mD, mU), mL);                                       \
        float sd = ldexpf(1.0f, mD - off);                                    \
        float su = ldexpf(1.0f, mU - off);                                    \
        float sl = ldexpf(1.0f, mL - off);                                    \
        float dm  = fmaf(qd1,P0.y, qd0*P0.x) + fmaf(qd3,P0.w, qd2*P0.z);      \
        float dx  = fmaf(qu1,P1.y, qu0*P1.x) + fmaf(qu3,P1.w, qu2*P1.z);      \
        float dy  = fmaf(ql1,P2.y, ql0*P2.x) + fmaf(ql3,P2.w, ql2*P2.z);      \
        float ds2 = fmaf(qd1,P3.y, qd0*P3.x) + fmaf(qd3,P3.w, qd2*P3.z);      \
        float g0 = dm *sd, g1 = dx*su, g2 = dy*sl, g3 = ds2*sd;               \
        float gmax = fmaxf(fmaxf(g0,g1), fmaxf(g2,g3));                       \
        int e = (int)(__float_as_uint(gmax) >> 23) - 126;                     \
        float qn0 = ldexpf(g0, 1-e), qn1 = ldexpf(g1, 1-e);                   \
        float qn2 = ldexpf(g2, 1-e), qn3 = ldexpf(g3, 1-e);                   \
        int mn = off + e - 1;                                                 \
        const bool valid_ = (jq_ >= 1) && (jq_ <= MM);                        \
        if (!valid_) { qn0=qn1=qn2=qn3=0.f; mn=NEGI; }                        \
        if (lane == 63) {                                                     \
            if (isProd) {                                                     \
                *(float4*)&recOut[sb_ + u_][0] = make_float4(qn0,qn1,qn2,qn3);\
                recOut[sb_ + u_][4] = __int_as_float(mn);                     \
            } else if (jq_ == MM) {                                           \
                out[0] = LN2f * ((float)mn + log2f((qn0+qn1)+(qn2+qn3)));     \
            }                                                                 \
        }                                                                     \
        int bmv = NEGI; float b0=0.f,b1=0.f,b2=0.f,b3=0.f;                    \
        if (isCons) {                                                         \
            float4 bb = *(const float4*)&recIn[sb_ + u_][0];                  \
            bmv = __float_as_int(recIn[sb_ + u_][4]);                         \
            b0=bb.x; b1=bb.y; b2=bb.z; b3=bb.w;                               \
        }                                                                     \
        mD = mU; qd0=qu0; qd1=qu1; qd2=qu2; qd3=qu3;                          \
        mU  = dpp_shr1_i(bmv, mn);                                            \
        qu0 = dpp_shr1_f(b0, qn0);                                            \
        qu1 = dpp_shr1_f(b1, qn1);                                            \
        qu2 = dpp_shr1_f(b2, qn2);                                            \
        qu3 = dpp_shr1_f(b3, qn3);                                            \
        mL = mn; ql0=qn0; ql1=qn1; ql2=qn2; ql3=qn3;                          \
    }                                                                         \
    asm volatile("" ::: "memory");                                            \
    if (lane == 0) {                                                          \
        *(volatile int*)&flags[F_CDONE] = (H);  /* LDS in-order per wave */   \
        st_cohi(cp, (H));                       /* pace producers */          \
    }                                                                         \
} while (0)

__global__ __launch_bounds__(256, 1) void viterbi_r13(
    const float* __restrict__ theta, const float* __restrict__ A,
    float* __restrict__ out, float* __restrict__ bnd, int* __restrict__ prog,
    int* __restrict__ cpG, int* __restrict__ rfG, float* __restrict__ ringG)
{
    __shared__ float  recIn[32][8];
    __shared__ float  recOut[32][8];
    __shared__ int    flags[16];
    extern __shared__ char dynpad[];            // 96 KB pad -> 1 block/CU
    (void)dynpad;

    const int tid  = threadIdx.x;
    const int wv   = tid >> 6;
    const int lane = tid & 63;
    const int bid  = blockIdx.x;

    if (tid < 16) flags[tid] = -1;
    __syncthreads();

    if (bid >= 16) {
        // ===================== producer blocks (4 waves) ====================
        const int k     = bid & 7;           // XCD (heuristic)
        const int idx   = (bid - 16) >> 3;   // 0..29 within XCD
        const int s     = 2*k + (idx >= PPS);
        const int pslot = idx % PPS;
        const int u2    = wv;                // tau within hc
        const int row   = s*64 + lane;
        const float4* A4 = (const float4*)A;
        const float4* T4 = (const float4*)theta;
        const int* cp = cpG + s*16;
        for (int h = pslot; h < HCT; h += PPS) {
            while (ld_cohi(cp) < h - DEPTH) __builtin_amdgcn_s_sleep(1);
            const int tau = 4*h + u2;
            int c = tau - lane; c = c < 0 ? 0 : (c > MM-1 ? MM-1 : c);
            const float4* Ar = A4 + ((size_t)row*MM + (size_t)c)*4;
            float4 a0 = Ar[0], a1 = Ar[1], a2 = Ar[2], a3 = Ar[3];
            float4 th = T4[(size_t)row*MM + (size_t)c];
            float4 p0, p1, p2, p3;       // theta-folded exp-domain potentials
            p0.x=exp2f((a0.x+th.x)*LOG2E); p0.y=exp2f((a0.y+th.x)*LOG2E);
            p0.z=exp2f((a0.z+th.x)*LOG2E); p0.w=exp2f((a0.w+th.x)*LOG2E);
            p1.x=exp2f((a1.x+th.y)*LOG2E); p1.y=exp2f((a1.y+th.y)*LOG2E);
            p1.z=exp2f((a1.z+th.y)*LOG2E); p1.w=exp2f((a1.w+th.y)*LOG2E);
            p2.x=exp2f((a2.x+th.z)*LOG2E); p2.y=exp2f((a2.y+th.z)*LOG2E);
            p2.z=exp2f((a2.z+th.z)*LOG2E); p2.w=exp2f((a2.w+th.z)*LOG2E);
            p3.x=exp2f((a3.x+th.w)*LOG2E); p3.y=exp2f((a3.y+th.w)*LOG2E);
            p3.z=exp2f((a3.z+th.w)*LOG2E); p3.w=exp2f((a3.w+th.w)*LOG2E);
            float* dst = ringG + ((size_t)(s*DEPTH + (h & (DEPTH-1))) << 12)
                               + (size_t)((u2*4)*64 + lane)*4;
            st_cohf(dst+0,   p0.x); st_cohf(dst+1,   p0.y);
            st_cohf(dst+2,   p0.z); st_cohf(dst+3,   p0.w);
            st_cohf(dst+256, p1.x); st_cohf(dst+257, p1.y);
            st_cohf(dst+258, p1.z); st_cohf(dst+259, p1.w);
            st_cohf(dst+512, p2.x); st_cohf(dst+513, p2.y);
            st_cohf(dst+514, p2.z); st_cohf(dst+515, p2.w);
            st_cohf(dst+768, p3.x); st_cohf(dst+769, p3.y);
            st_cohf(dst+770, p3.z); st_cohf(dst+771, p3.w);
            asm volatile("s_waitcnt vmcnt(0)" ::: "memory");
            if (lane == 0)
                st_cohi(rfG + (size_t)(s*DEPTH + (h & (DEPTH-1)))*16 + u2, h);
        }
        return;
    }

    // ===================== pipeline blocks =====================
    const int strip = ((bid & 7) << 1) | (bid >> 3);
    const bool isCons = (strip > 0);
    const bool isProd = (strip < 15);

    float* Prec = bnd + (size_t)strip * MM * 8;
    const float* Crec = bnd + (size_t)(strip - 1) * MM * 8;
    int* myflag = prog + strip * 32;
    const int* upflag = prog + (strip - 1) * 32;

    if (wv == 0) {
        // ============ chain wave: HW-counted global->reg pipeline ===========
        __builtin_amdgcn_s_setprio(1);
        const int r = lane;
        int   mL = NEGI, mU = NEGI, mD = NEGI;
        float ql0=0,ql1=0,ql2=0,ql3=0;
        float qu0=0,qu1=0,qu2=0,qu3=0;
        float qd0=0,qd1=0,qd2=0,qd3=0;
        if (strip == 0 && lane == 0) { mD = 0; qd0=qd1=qd2=qd3=1.f; }
        if (isCons) {
            while (ld_cohi(upflag) < 1) __builtin_amdgcn_s_sleep(1);
            asm volatile("" ::: "memory");
            qu0 = ld_cohf(Crec+0); qu1 = ld_cohf(Crec+1);
            qu2 = ld_cohf(Crec+2); qu3 = ld_cohf(Crec+3);
            mU  = ld_cohi((const int*)Crec + 4);
        }
        int* cp = cpG + strip*16;
        const int* rfS = rfG + (size_t)strip * DEPTH * 16;
        const char* ringS = (const char*)ringG + ((size_t)strip * DEPTH << 14);
        if (lane == 0) st_cohi(cp, -1);      // unblock producers h < DEPTH

        f32x4 pA[16], pB[16];
        i32x4 fA = {-2,-2,-2,-2}, fB = {-2,-2,-2,-2};
        // prologue: slots 0,1 data; flags for 2,3 in flight
        CHECK_FLAG(fA, 0); ISSUE_DATA(pA, 0);
        CHECK_FLAG(fB, 1); ISSUE_DATA(pB, 1);
        ISSUE_FLAG(fA, 2); ISSUE_FLAG(fB, 3);
        // body 0 (one-time drain; producers are ahead)
        CHUNKSPIN(0);
        WAITV(1);  CHECK_FLAG(fA, 2); ISSUE_FLAG(fA, 4);
        COMPUTEHC(0, pA); ISSUE_DATA(pA, 2);
        // body 1
        WAITV(18); CHECK_FLAG(fB, 3); ISSUE_FLAG(fB, 5);
        COMPUTEHC(1, pB); ISSUE_DATA(pB, 3);
        // steady state: 18 vmem ops/body -> A-wait 35, D-wait 19
        for (int h = 2; h < HCT; h += 2) {
            CHUNKSPIN(h);
            WAITV(35); CHECK_FLAG(fA, h+2); ISSUE_FLAG(fA, h+4);
            WAITV(19); COMPUTEHC(h, pA); ISSUE_DATA(pA, h+2);
            WAITV(35); CHECK_FLAG(fB, h+3); ISSUE_FLAG(fB, h+5);
            WAITV(19); COMPUTEHC(h+1, pB); ISSUE_DATA(pB, h+3);
        }
    } else if (wv == 1) {
        // ===================== out-comms wave =====================
        if (!isProd) return;
        const int rec0 = lane / 5, wd0 = lane % 5;
        const int rec1 = (lane+64) / 5, wd1 = (lane+64) % 5;
        const bool on1 = (lane + 64) < 80;
        for (int cc = 0; cc < NCH; cc += 2) {
            while (lds_acq(&flags[F_CDONE]) < 2*cc + 3) __builtin_amdgcn_s_sleep(1);
            {
                int col = 8*(cc + (rec0 >> 3)) + (rec0 & 7) - 62;
                float v = recOut[(cc & 3)*8 + rec0][wd0];
                if (col >= 1 && col <= MM) st_cohf(Prec + (size_t)(col-1)*8 + wd0, v);
            }
            if (on1) {
                int col = 8*(cc + (rec1 >> 3)) + (rec1 & 7) - 62;
                float v = recOut[(cc & 3)*8 + rec1][wd1];
                if (col >= 1 && col <= MM) st_cohf(Prec + (size_t)(col-1)*8 + wd1, v);
            }
            asm volatile("s_waitcnt vmcnt(0)" ::: "memory");
            int done = 8*(cc + 1) - 55; if (done > MM) done = MM;
            if (done >= 1 && lane == 0) st_cohi(myflag, done);
            if (lane == 0) lds_rel(&flags[F_OPUB], cc + 1);
        }
    } else if (wv == 2) {
        // ===================== in-comms wave =====================
        if (!isCons) return;
        const int rec0 = lane / 5, wd0 = lane % 5;
        const int rec1 = (lane+64) / 5, wd1 = (lane+64) % 5;
        const bool on1 = (lane + 64) < 80;
        for (int cc = 0; cc < NCH; cc += 2) {
            while (lds_acq(&flags[F_CDONE]) < 2*cc - 3) __builtin_amdgcn_s_sleep(1);
            int need = 8*cc + 17; if (need > MM) need = MM;
            while (ld_cohi(upflag) < need) __builtin_amdgcn_s_sleep(1);
            asm volatile("" ::: "memory");
            {
                int col = 8*cc + 2 + rec0; if (col > MM) col = MM;
                float v = ld_cohf(Crec + (size_t)(col-1)*8 + wd0);
                recIn[(cc & 3)*8 + rec0][wd0] = v;
            }
            if (on1) {
                int col = 8*cc + 2 + rec1; if (col > MM) col = MM;
                float v = ld_cohf(Crec + (size_t)(col-1)*8 + wd1);
                recIn[(cc & 3)*8 + rec1][wd1] = v;
            }
            if (lane == 0) lds_rel(&flags[F_RIN], cc + 1);
        }
    }
    // wv == 3: idle
}

extern "C" void kernel_launch(void* const* d_in, const int* in_sizes, int n_in,
                              void* d_out, int out_size, void* d_ws, size_t ws_size,
                              hipStream_t stream) {
    const float* theta = (const float*)d_in[0];   // [1024,1024,4] f32
    const float* A     = (const float*)d_in[1];   // [1024,1024,4,4] f32
    float* out = (float*)d_out;                   // [1] f32
    // ws layout (0xAA poison -> all flags/counters negative -> safe spins):
    //   [0, 512K)        boundary records [16][1024][8] f32
    //   [512K, 512K+4K)  record progress flags prog[16*32]
    //   [+4K, +8K)       chain progress cpG[16*16]
    //   [+8K, +40K)      ring flags rfG[16*32*16]
    //   [64K-aligned 8M) P ring ringG: 16 strips * 32 slots * 16 KB
    char* base = (char*)d_ws;
    float* bnd  = (float*)base;
    int*   prog = (int*)(base + (size_t)512*1024);
    int*   cpG  = (int*)(base + (size_t)512*1024 + 4*1024);
    int*   rfG  = (int*)(base + (size_t)512*1024 + 8*1024);
    float* ring = (float*)(base + (size_t)512*1024 + 64*1024);
    // 96 KB dynamic LDS pad: 1 block/CU for all 256 blocks.
    viterbi_r13<<<256, 256, 96*1024, stream>>>(theta, A, out, bnd, prog,
                                               cpG, rfG, ring);
}

// Round 6
// 608.181 us; speedup vs baseline: 1.3459x; 1.0963x over previous
//
#include <hip/hip_runtime.h>
#include <stdint.h>

// Softmax-Viterbi forward, 1024x1024, S=4.
// R14: slim the chain's per-step instruction stream. Evidence (R13): VALUBusy
// 1.70% x 1024 SIMDs ~= 17.4 busy SIMD-equivalents ~= the 16 chain waves ->
// chain SIMDs issue ~100% of cycles: the chain is VALU-ISSUE-BOUND (~85-90
// instr/step x 2cy). Total ~= 392*T_chunk + 15*L_comm, so T_chunk dominates.
// Changes (chain only; prefetch cadence/counts, comms, producers frozen):
//  - 3-phase h-loop: clamped hc 0..15, FAST hc 16..255 (taus 64..1023, all
//    lanes valid -> no jq/valid/cndmask/out-check), clamped hc 256..271.
//  - d-sums as serial 4-fma chains (4 instr vs 5; issue-bound so net win).
//  - deferred normalization: normalize every OTHER step. Power-of-2 scaling
//    is exact in fp32 -> bit-identical combine; skip deletes gmax/e/ldexpx4
//    (~10 instr + 16cy dep) from half the steps. One unnorm step grows q by
//    <= 2^19 vs 2^127 range; records with unnorm (q,m) are valid generically.

typedef float f32x4 __attribute__((ext_vector_type(4)));
typedef int   i32x4 __attribute__((ext_vector_type(4)));

#define MM    1024
#define LOG2E 1.4426950408889634f
#define LN2f  0.6931471805599453f
#define NEGI  (-1073741824)
#define NCH   136
#define HCT   (NCH*2)                // 272 half-chunks, 4 steps each
#define DEPTH 32                     // global P-ring depth in half-chunks
#define PPS   15                     // producer blocks per strip

#define F_RIN   0
#define F_CDONE 1
#define F_OPUB  2

__device__ __forceinline__ float ld_cohf(const float* p) {
    return __hip_atomic_load(p, __ATOMIC_RELAXED, __HIP_MEMORY_SCOPE_AGENT);
}
__device__ __forceinline__ int ld_cohi(const int* p) {
    return __hip_atomic_load(p, __ATOMIC_RELAXED, __HIP_MEMORY_SCOPE_AGENT);
}
__device__ __forceinline__ void st_cohf(float* p, float v) {
    __hip_atomic_store(p, v, __ATOMIC_RELAXED, __HIP_MEMORY_SCOPE_AGENT);
}
__device__ __forceinline__ void st_cohi(int* p, int v) {
    __hip_atomic_store(p, v, __ATOMIC_RELAXED, __HIP_MEMORY_SCOPE_AGENT);
}
__device__ __forceinline__ int lds_acq(const int* p) {
    return __hip_atomic_load(p, __ATOMIC_ACQUIRE, __HIP_MEMORY_SCOPE_WORKGROUP);
}
__device__ __forceinline__ void lds_rel(int* p, int v) {
    __hip_atomic_store(p, v, __ATOMIC_RELEASE, __HIP_MEMORY_SCOPE_WORKGROUP);
}

// DPP wave_shr1: lane n <- lane n-1; lane 0 <- oldv (bound_ctrl=false keeps old).
__device__ __forceinline__ int dpp_shr1_i(int oldv, int src) {
    return __builtin_amdgcn_update_dpp(oldv, src, 0x138, 0xF, 0xF, false);
}
__device__ __forceinline__ float dpp_shr1_f(float oldv, float src) {
    return __int_as_float(__builtin_amdgcn_update_dpp(
        __float_as_int(oldv), __float_as_int(src), 0x138, 0xF, 0xF, false));
}

// ---------------- chain-side pipeline macros ----------------
#define WAITV(N) do {                                                         \
    asm volatile("s_waitcnt vmcnt(" #N ")" ::: "memory");                     \
    __builtin_amdgcn_sched_barrier(0);                                        \
} while (0)

#define ISSUE_FLAG(FX, H) do {                                                \
    const int hf_ = ((H) < HCT ? (H) : (HCT-1));                              \
    const int* rp_ = rfS + (size_t)(hf_ & (DEPTH-1)) * 16;                    \
    asm volatile("global_load_dwordx4 %0, %1, off sc0 sc1"                    \
                 : "=v"(FX) : "v"(rp_) : "memory");                           \
} while (0)

#define CHECK_FLAG(FX, H) do {                                                \
    const int hv_ = ((H) < HCT ? (H) : (HCT-1));                              \
    if (!(FX.x >= hv_ && FX.y >= hv_ && FX.z >= hv_ && FX.w >= hv_)) {        \
        const int* rp_ = rfS + (size_t)(hv_ & (DEPTH-1)) * 16;                \
        for (;;) {                                                            \
            asm volatile("global_load_dwordx4 %0, %1, off sc0 sc1\n\t"        \
                         "s_waitcnt vmcnt(0)"                                 \
                         : "=v"(FX) : "v"(rp_) : "memory");                   \
            if (FX.x >= hv_ && FX.y >= hv_ && FX.z >= hv_ && FX.w >= hv_)     \
                break;                                                        \
            __builtin_amdgcn_s_sleep(2);                                      \
        }                                                                     \
    }                                                                         \
    asm volatile("" ::: "memory");                                            \
} while (0)

#define ISSUE_DATA(PX, H) do {                                                \
    const int hcl_ = ((H) < HCT ? (H) : (HCT-1));                             \
    const char* b0_ = ringS + ((size_t)(hcl_ & (DEPTH-1)) << 14)              \
                            + (size_t)lane * 16;                              \
    const char* b1_ = b0_ + 4096;                                             \
    const char* b2_ = b0_ + 8192;                                             \
    const char* b3_ = b0_ + 12288;                                            \
    asm volatile("global_load_dwordx4 %0, %1, off sc0 sc1"              : "=v"(PX[0])  : "v"(b0_) : "memory"); \
    asm volatile("global_load_dwordx4 %0, %1, off offset:1024 sc0 sc1"  : "=v"(PX[1])  : "v"(b0_) : "memory"); \
    asm volatile("global_load_dwordx4 %0, %1, off offset:2048 sc0 sc1"  : "=v"(PX[2])  : "v"(b0_) : "memory"); \
    asm volatile("global_load_dwordx4 %0, %1, off offset:3072 sc0 sc1"  : "=v"(PX[3])  : "v"(b0_) : "memory"); \
    asm volatile("global_load_dwordx4 %0, %1, off sc0 sc1"              : "=v"(PX[4])  : "v"(b1_) : "memory"); \
    asm volatile("global_load_dwordx4 %0, %1, off offset:1024 sc0 sc1"  : "=v"(PX[5])  : "v"(b1_) : "memory"); \
    asm volatile("global_load_dwordx4 %0, %1, off offset:2048 sc0 sc1"  : "=v"(PX[6])  : "v"(b1_) : "memory"); \
    asm volatile("global_load_dwordx4 %0, %1, off offset:3072 sc0 sc1"  : "=v"(PX[7])  : "v"(b1_) : "memory"); \
    asm volatile("global_load_dwordx4 %0, %1, off sc0 sc1"              : "=v"(PX[8])  : "v"(b2_) : "memory"); \
    asm volatile("global_load_dwordx4 %0, %1, off offset:1024 sc0 sc1"  : "=v"(PX[9])  : "v"(b2_) : "memory"); \
    asm volatile("global_load_dwordx4 %0, %1, off offset:2048 sc0 sc1"  : "=v"(PX[10]) : "v"(b2_) : "memory"); \
    asm volatile("global_load_dwordx4 %0, %1, off offset:3072 sc0 sc1"  : "=v"(PX[11]) : "v"(b2_) : "memory"); \
    asm volatile("global_load_dwordx4 %0, %1, off sc0 sc1"              : "=v"(PX[12]) : "v"(b3_) : "memory"); \
    asm volatile("global_load_dwordx4 %0, %1, off offset:1024 sc0 sc1"  : "=v"(PX[13]) : "v"(b3_) : "memory"); \
    asm volatile("global_load_dwordx4 %0, %1, off offset:2048 sc0 sc1"  : "=v"(PX[14]) : "v"(b3_) : "memory"); \
    asm volatile("global_load_dwordx4 %0, %1, off offset:3072 sc0 sc1"  : "=v"(PX[15]) : "v"(b3_) : "memory"); \
} while (0)

#define CHUNKSPIN(H) do {                                                     \
    if (((H) & 1) == 0) {                                                     \
        const int cc_ = (H) >> 1;                                             \
        if (isCons) while (lds_acq(&flags[F_RIN]) < cc_) {}                   \
        if (isProd) while (lds_acq(&flags[F_OPUB]) < cc_ - 3) {}              \
    }                                                                         \
} while (0)

// One cell-step. DO_CLAMP: boundary tau handling. DO_NORM: renormalize
// (power-of-2 exact; skipping is bit-identical in the combine arithmetic).
#define VSTEP(H, U, PX, DO_CLAMP, DO_NORM) do {                               \
    const int sb_ = (((H) >> 1) & 3) * 8 + ((H) & 1) * 4 + (U);               \
    f32x4 P0 = PX[(U)*4+0], P1 = PX[(U)*4+1];                                 \
    f32x4 P2 = PX[(U)*4+2], P3 = PX[(U)*4+3];                                 \
    int off = max(max(mD, mU), mL);                                           \
    float sd = ldexpf(1.0f, mD - off);                                        \
    float su = ldexpf(1.0f, mU - off);                                        \
    float sl = ldexpf(1.0f, mL - off);                                        \
    float dm  = fmaf(qd3,P0.w, fmaf(qd2,P0.z, fmaf(qd1,P0.y, qd0*P0.x)));     \
    float dx  = fmaf(qu3,P1.w, fmaf(qu2,P1.z, fmaf(qu1,P1.y, qu0*P1.x)));     \
    float dy  = fmaf(ql3,P2.w, fmaf(ql2,P2.z, fmaf(ql1,P2.y, ql0*P2.x)));     \
    float ds2 = fmaf(qd3,P3.w, fmaf(qd2,P3.z, fmaf(qd1,P3.y, qd0*P3.x)));     \
    float qn0 = dm*sd, qn1 = dx*su, qn2 = dy*sl, qn3 = ds2*sd;                \
    int mn = off;                                                             \
    if (DO_NORM) {                                                            \
        float gmax = fmaxf(fmaxf(qn0,qn1), fmaxf(qn2,qn3));                   \
        int e = (int)(__float_as_uint(gmax) >> 23) - 126;                     \
        qn0 = ldexpf(qn0, 1-e); qn1 = ldexpf(qn1, 1-e);                       \
        qn2 = ldexpf(qn2, 1-e); qn3 = ldexpf(qn3, 1-e);                       \
        mn = off + e - 1;                                                     \
    }                                                                         \
    if (DO_CLAMP) {                                                           \
        const int jq_ = (H)*4 + (U) - r + 1;                                  \
        const bool valid_ = (jq_ >= 1) && (jq_ <= MM);                        \
        if (!valid_) { qn0=qn1=qn2=qn3=0.f; mn=NEGI; }                        \
        if (!isProd && lane == 63 && jq_ == MM)                               \
            out[0] = LN2f * ((float)mn + log2f((qn0+qn1)+(qn2+qn3)));         \
    }                                                                         \
    if (isProd && lane == 63) {                                               \
        *(float4*)&recOut[sb_][0] = make_float4(qn0,qn1,qn2,qn3);             \
        recOut[sb_][4] = __int_as_float(mn);                                  \
    }                                                                         \
    int bmv = NEGI; float b0=0.f,b1=0.f,b2=0.f,b3=0.f;                        \
    if (isCons) {                                                             \
        float4 bb = *(const float4*)&recIn[sb_][0];                           \
        bmv = __float_as_int(recIn[sb_][4]);                                  \
        b0=bb.x; b1=bb.y; b2=bb.z; b3=bb.w;                                   \
    }                                                                         \
    mD = mU; qd0=qu0; qd1=qu1; qd2=qu2; qd3=qu3;                              \
    mU  = dpp_shr1_i(bmv, mn);                                                \
    qu0 = dpp_shr1_f(b0, qn0);                                                \
    qu1 = dpp_shr1_f(b1, qn1);                                                \
    qu2 = dpp_shr1_f(b2, qn2);                                                \
    qu3 = dpp_shr1_f(b3, qn3);                                                \
    mL = mn; ql0=qn0; ql1=qn1; ql2=qn2; ql3=qn3;                              \
} while (0)

#define CHCTAIL(H) do {                                                       \
    asm volatile("" ::: "memory");                                            \
    if (lane == 0) {                                                          \
        *(volatile int*)&flags[F_CDONE] = (H);  /* LDS in-order per wave */   \
        st_cohi(cp, (H));                       /* pace producers */          \
    }                                                                         \
} while (0)

#define COMPUTEHC_C(H, PX) do {                                               \
    VSTEP(H, 0, PX, 1, 1); VSTEP(H, 1, PX, 1, 1);                             \
    VSTEP(H, 2, PX, 1, 1); VSTEP(H, 3, PX, 1, 1);                             \
    CHCTAIL(H);                                                               \
} while (0)

// FAST: all lanes valid; normalize every other step (last step normalized).
#define COMPUTEHC_F(H, PX) do {                                               \
    VSTEP(H, 0, PX, 0, 0); VSTEP(H, 1, PX, 0, 1);                             \
    VSTEP(H, 2, PX, 0, 0); VSTEP(H, 3, PX, 0, 1);                             \
    CHCTAIL(H);                                                               \
} while (0)

// steady-state body pair (18 vmem ops/body -> A-wait 35, D-wait 19)
#define CHAINBODY(H, CHC) do {                                                \
    CHUNKSPIN(H);                                                             \
    WAITV(35); CHECK_FLAG(fA, (H)+2); ISSUE_FLAG(fA, (H)+4);                  \
    WAITV(19); CHC((H), pA); ISSUE_DATA(pA, (H)+2);                           \
    WAITV(35); CHECK_FLAG(fB, (H)+3); ISSUE_FLAG(fB, (H)+5);                  \
    WAITV(19); CHC((H)+1, pB); ISSUE_DATA(pB, (H)+3);                         \
} while (0)

__global__ __launch_bounds__(256, 1) void viterbi_r14(
    const float* __restrict__ theta, const float* __restrict__ A,
    float* __restrict__ out, float* __restrict__ bnd, int* __restrict__ prog,
    int* __restrict__ cpG, int* __restrict__ rfG, float* __restrict__ ringG)
{
    __shared__ float  recIn[32][8];
    __shared__ float  recOut[32][8];
    __shared__ int    flags[16];
    extern __shared__ char dynpad[];            // 96 KB pad -> 1 block/CU
    (void)dynpad;

    const int tid  = threadIdx.x;
    const int wv   = tid >> 6;
    const int lane = tid & 63;
    const int bid  = blockIdx.x;

    if (tid < 16) flags[tid] = -1;
    __syncthreads();

    if (bid >= 16) {
        // ===================== producer blocks (4 waves) ====================
        const int k     = bid & 7;           // XCD (heuristic)
        const int idx   = (bid - 16) >> 3;   // 0..29 within XCD
        const int s     = 2*k + (idx >= PPS);
        const int pslot = idx % PPS;
        const int u2    = wv;                // tau within hc
        const int row   = s*64 + lane;
        const float4* A4 = (const float4*)A;
        const float4* T4 = (const float4*)theta;
        const int* cp = cpG + s*16;
        for (int h = pslot; h < HCT; h += PPS) {
            while (ld_cohi(cp) < h - DEPTH) __builtin_amdgcn_s_sleep(1);
            const int tau = 4*h + u2;
            int c = tau - lane; c = c < 0 ? 0 : (c > MM-1 ? MM-1 : c);
            const float4* Ar = A4 + ((size_t)row*MM + (size_t)c)*4;
            float4 a0 = Ar[0], a1 = Ar[1], a2 = Ar[2], a3 = Ar[3];
            float4 th = T4[(size_t)row*MM + (size_t)c];
            float4 p0, p1, p2, p3;       // theta-folded exp-domain potentials
            p0.x=exp2f((a0.x+th.x)*LOG2E); p0.y=exp2f((a0.y+th.x)*LOG2E);
            p0.z=exp2f((a0.z+th.x)*LOG2E); p0.w=exp2f((a0.w+th.x)*LOG2E);
            p1.x=exp2f((a1.x+th.y)*LOG2E); p1.y=exp2f((a1.y+th.y)*LOG2E);
            p1.z=exp2f((a1.z+th.y)*LOG2E); p1.w=exp2f((a1.w+th.y)*LOG2E);
            p2.x=exp2f((a2.x+th.z)*LOG2E); p2.y=exp2f((a2.y+th.z)*LOG2E);
            p2.z=exp2f((a2.z+th.z)*LOG2E); p2.w=exp2f((a2.w+th.z)*LOG2E);
            p3.x=exp2f((a3.x+th.w)*LOG2E); p3.y=exp2f((a3.y+th.w)*LOG2E);
            p3.z=exp2f((a3.z+th.w)*LOG2E); p3.w=exp2f((a3.w+th.w)*LOG2E);
            float* dst = ringG + ((size_t)(s*DEPTH + (h & (DEPTH-1))) << 12)
                               + (size_t)((u2*4)*64 + lane)*4;
            st_cohf(dst+0,   p0.x); st_cohf(dst+1,   p0.y);
            st_cohf(dst+2,   p0.z); st_cohf(dst+3,   p0.w);
            st_cohf(dst+256, p1.x); st_cohf(dst+257, p1.y);
            st_cohf(dst+258, p1.z); st_cohf(dst+259, p1.w);
            st_cohf(dst+512, p2.x); st_cohf(dst+513, p2.y);
            st_cohf(dst+514, p2.z); st_cohf(dst+515, p2.w);
            st_cohf(dst+768, p3.x); st_cohf(dst+769, p3.y);
            st_cohf(dst+770, p3.z); st_cohf(dst+771, p3.w);
            asm volatile("s_waitcnt vmcnt(0)" ::: "memory");
            if (lane == 0)
                st_cohi(rfG + (size_t)(s*DEPTH + (h & (DEPTH-1)))*16 + u2, h);
        }
        return;
    }

    // ===================== pipeline blocks =====================
    const int strip = ((bid & 7) << 1) | (bid >> 3);
    const bool isCons = (strip > 0);
    const bool isProd = (strip < 15);

    float* Prec = bnd + (size_t)strip * MM * 8;
    const float* Crec = bnd + (size_t)(strip - 1) * MM * 8;
    int* myflag = prog + strip * 32;
    const int* upflag = prog + (strip - 1) * 32;

    if (wv == 0) {
        // ============ chain wave: HW-counted global->reg pipeline ===========
        __builtin_amdgcn_s_setprio(1);
        const int r = lane;
        int   mL = NEGI, mU = NEGI, mD = NEGI;
        float ql0=0,ql1=0,ql2=0,ql3=0;
        float qu0=0,qu1=0,qu2=0,qu3=0;
        float qd0=0,qd1=0,qd2=0,qd3=0;
        if (strip == 0 && lane == 0) { mD = 0; qd0=qd1=qd2=qd3=1.f; }
        if (isCons) {
            while (ld_cohi(upflag) < 1) __builtin_amdgcn_s_sleep(1);
            asm volatile("" ::: "memory");
            qu0 = ld_cohf(Crec+0); qu1 = ld_cohf(Crec+1);
            qu2 = ld_cohf(Crec+2); qu3 = ld_cohf(Crec+3);
            mU  = ld_cohi((const int*)Crec + 4);
        }
        int* cp = cpG + strip*16;
        const int* rfS = rfG + (size_t)strip * DEPTH * 16;
        const char* ringS = (const char*)ringG + ((size_t)strip * DEPTH << 14);
        if (lane == 0) st_cohi(cp, -1);      // unblock producers h < DEPTH

        f32x4 pA[16], pB[16];
        i32x4 fA = {-2,-2,-2,-2}, fB = {-2,-2,-2,-2};
        // prologue: slots 0,1 data; flags for 2,3 in flight
        CHECK_FLAG(fA, 0); ISSUE_DATA(pA, 0);
        CHECK_FLAG(fB, 1); ISSUE_DATA(pB, 1);
        ISSUE_FLAG(fA, 2); ISSUE_FLAG(fB, 3);
        // body 0 (one-time drain; producers are ahead)
        CHUNKSPIN(0);
        WAITV(1);  CHECK_FLAG(fA, 2); ISSUE_FLAG(fA, 4);
        COMPUTEHC_C(0, pA); ISSUE_DATA(pA, 2);
        // body 1
        WAITV(18); CHECK_FLAG(fB, 3); ISSUE_FLAG(fB, 5);
        COMPUTEHC_C(1, pB); ISSUE_DATA(pB, 3);
        // clamped prologue: hc 2..15 (taus 8..63)
        for (int h = 2; h < 16; h += 2)  CHAINBODY(h, COMPUTEHC_C);
        // fast body: hc 16..255 (taus 64..1023, all lanes valid)
        for (int h = 16; h < 256; h += 2) CHAINBODY(h, COMPUTEHC_F);
        // clamped epilogue: hc 256..271 (taus 1024..1087)
        for (int h = 256; h < HCT; h += 2) CHAINBODY(h, COMPUTEHC_C);
    } else if (wv == 1) {
        // ===================== out-comms wave =====================
        if (!isProd) return;
        const int rec0 = lane / 5, wd0 = lane % 5;
        const int rec1 = (lane+64) / 5, wd1 = (lane+64) % 5;
        const bool on1 = (lane + 64) < 80;
        for (int cc = 0; cc < NCH; cc += 2) {
            while (lds_acq(&flags[F_CDONE]) < 2*cc + 3) __builtin_amdgcn_s_sleep(1);
            {
                int col = 8*(cc + (rec0 >> 3)) + (rec0 & 7) - 62;
                float v = recOut[(cc & 3)*8 + rec0][wd0];
                if (col >= 1 && col <= MM) st_cohf(Prec + (size_t)(col-1)*8 + wd0, v);
            }
            if (on1) {
                int col = 8*(cc + (rec1 >> 3)) + (rec1 & 7) - 62;
                float v = recOut[(cc & 3)*8 + rec1][wd1];
                if (col >= 1 && col <= MM) st_cohf(Prec + (size_t)(col-1)*8 + wd1, v);
            }
            asm volatile("s_waitcnt vmcnt(0)" ::: "memory");
            int done = 8*(cc + 1) - 55; if (done > MM) done = MM;
            if (done >= 1 && lane == 0) st_cohi(myflag, done);
            if (lane == 0) lds_rel(&flags[F_OPUB], cc + 1);
        }
    } else if (wv == 2) {
        // ===================== in-comms wave =====================
        if (!isCons) return;
        const int rec0 = lane / 5, wd0 = lane % 5;
        const int rec1 = (lane+64) / 5, wd1 = (lane+64) % 5;
        const bool on1 = (lane + 64) < 80;
        for (int cc = 0; cc < NCH; cc += 2) {
            while (lds_acq(&flags[F_CDONE]) < 2*cc - 3) __builtin_amdgcn_s_sleep(1);
            int need = 8*cc + 17; if (need > MM) need = MM;
            while (ld_cohi(upflag) < need) __builtin_amdgcn_s_sleep(1);
            asm volatile("" ::: "memory");
            {
                int col = 8*cc + 2 + rec0; if (col > MM) col = MM;
                float v = ld_cohf(Crec + (size_t)(col-1)*8 + wd0);
                recIn[(cc & 3)*8 + rec0][wd0] = v;
            }
            if (on1) {
                int col = 8*cc + 2 + rec1; if (col > MM) col = MM;
                float v = ld_cohf(Crec + (size_t)(col-1)*8 + wd1);
                recIn[(cc & 3)*8 + rec1][wd1] = v;
            }
            if (lane == 0) lds_rel(&flags[F_RIN], cc + 1);
        }
    }
    // wv == 3: idle
}

extern "C" void kernel_launch(void* const* d_in, const int* in_sizes, int n_in,
                              void* d_out, int out_size, void* d_ws, size_t ws_size,
                              hipStream_t stream) {
    const float* theta = (const float*)d_in[0];   // [1024,1024,4] f32
    const float* A     = (const float*)d_in[1];   // [1024,1024,4,4] f32
    float* out = (float*)d_out;                   // [1] f32
    // ws layout (0xAA poison -> all flags/counters negative -> safe spins):
    //   [0, 512K)        boundary records [16][1024][8] f32
    //   [512K, 512K+4K)  record progress flags prog[16*32]
    //   [+4K, +8K)       chain progress cpG[16*16]
    //   [+8K, +40K)      ring flags rfG[16*32*16]
    //   [64K-aligned 8M) P ring ringG: 16 strips * 32 slots * 16 KB
    char* base = (char*)d_ws;
    float* bnd  = (float*)base;
    int*   prog = (int*)(base + (size_t)512*1024);
    int*   cpG  = (int*)(base + (size_t)512*1024 + 4*1024);
    int*   rfG  = (int*)(base + (size_t)512*1024 + 8*1024);
    float* ring = (float*)(base + (size_t)512*1024 + 64*1024);
    // 96 KB dynamic LDS pad: 1 block/CU for all 256 blocks.
    viterbi_r14<<<256, 256, 96*1024, stream>>>(theta, A, out, bnd, prog,
                                               cpG, rfG, ring);
}